// Round 1
// 383.679 us; speedup vs baseline: 1.0427x; 1.0427x over previous
//
#include <hip/hip_runtime.h>

#define NN 163842
#define NE 983040
#define NB 641   // ceil(NN/256)

using short8   = __attribute__((ext_vector_type(8))) short;
using ushort8v = __attribute__((ext_vector_type(8))) unsigned short;
using f32x4    = __attribute__((ext_vector_type(4))) float;

// ---------------- degree count (int) ----------------
__global__ __launch_bounds__(256) void deg_count(const int* __restrict__ dst,
                                                 int* __restrict__ degi, int E) {
    int e = blockIdx.x * 256 + threadIdx.x;
    if (e < E) atomicAdd(&degi[dst[e]], 1);
}

// ---------------- exclusive scan of degi -> cursor ----------------
__global__ __launch_bounds__(256) void scan1(const int* __restrict__ degi,
                                             int* __restrict__ cursor,
                                             int* __restrict__ bsum, int n) {
    __shared__ int tmp[256];
    int t = threadIdx.x;
    int i = blockIdx.x * 256 + t;
    int v = (i < n) ? degi[i] : 0;
    tmp[t] = v;
    __syncthreads();
    for (int o = 1; o < 256; o <<= 1) {
        int x = (t >= o) ? tmp[t - o] : 0;
        __syncthreads();
        tmp[t] += x;
        __syncthreads();
    }
    if (i < n) cursor[i] = tmp[t] - v;            // exclusive
    if (t == 255) bsum[blockIdx.x] = tmp[255];    // block total
}

__global__ void scan2(int* __restrict__ bsum, int nb) {
    __shared__ int tmp[1024];
    int t = threadIdx.x;
    int v = (t < nb) ? bsum[t] : 0;
    tmp[t] = v;
    __syncthreads();
    for (int o = 1; o < 1024; o <<= 1) {
        int x = (t >= o) ? tmp[t - o] : 0;
        __syncthreads();
        tmp[t] += x;
        __syncthreads();
    }
    if (t < nb) bsum[t] = tmp[t] - v;
}

__global__ __launch_bounds__(256) void scan3(int* __restrict__ cursor,
                                             const int* __restrict__ bsum, int n) {
    int i = blockIdx.x * 256 + threadIdx.x;
    if (i < n) cursor[i] += bsum[blockIdx.x];
}

static __device__ __forceinline__ float3 gauss3(float ex, float ey,
                                                const float* __restrict__ mu,
                                                const float* __restrict__ sg) {
    float3 r;
    float dx, dy;
    dx = ex - mu[0]; dy = ey - mu[1];
    r.x = __expf(-0.5f * (dx * dx / (1e-15f + sg[0] * sg[0]) + dy * dy / (1e-15f + sg[1] * sg[1])));
    dx = ex - mu[2]; dy = ey - mu[3];
    r.y = __expf(-0.5f * (dx * dx / (1e-15f + sg[2] * sg[2]) + dy * dy / (1e-15f + sg[3] * sg[3])));
    dx = ex - mu[4]; dy = ey - mu[5];
    r.z = __expf(-0.5f * (dx * dx / (1e-15f + sg[4] * sg[4]) + dy * dy / (1e-15f + sg[5] * sg[5])));
    return r;
}

static __device__ __forceinline__ unsigned short bf16rne(float x) {
    unsigned u = __float_as_uint(x);
    u += 0x7FFFu + ((u >> 16) & 1u);      // round-to-nearest-even
    return (unsigned short)(u >> 16);
}

static __device__ __forceinline__ float bf2f(unsigned short u) {
    return __uint_as_float(((unsigned)u) << 16);
}

// ---- scatter + ALL per-layer gaussians, MERGED with vectorized x->bf16 pad ----
// blocks [0, EBLK): per-edge scatter; blocks [EBLK, EBLK+PB): pad x [N,22] -> xp [N,32] bf16.
__global__ __launch_bounds__(256) void scatter_pad(const int* __restrict__ src,
                                                   const int* __restrict__ dst,
                                                   const float* __restrict__ ea,
                                                   int* __restrict__ cursor,
                                                   const float* __restrict__ mu0, const float* __restrict__ sg0,
                                                   const float* __restrict__ mu1, const float* __restrict__ sg1,
                                                   const float* __restrict__ mu2, const float* __restrict__ sg2,
                                                   float4* __restrict__ g0b,
                                                   float4* __restrict__ g1b,
                                                   float4* __restrict__ g2b,
                                                   const float* __restrict__ x,
                                                   unsigned short* __restrict__ xp,
                                                   int E, int EBLK, int n) {
    if ((int)blockIdx.x >= EBLK) {
        // ---- pad path: one thread per node, float2 loads + ushort8 stores ----
        int r = (blockIdx.x - EBLK) * 256 + threadIdx.x;
        if (r >= n) return;
        float v[22];
        const float2* x2 = (const float2*)(x + (size_t)r * 22);  // 88 B row, 8-aligned
#pragma unroll
        for (int j = 0; j < 11; ++j) *(float2*)(v + 2 * j) = x2[j];
        unsigned short* op = xp + (size_t)r * 32;
#pragma unroll
        for (int g8 = 0; g8 < 4; ++g8) {
            ushort8v o;
#pragma unroll
            for (int j = 0; j < 8; ++j) {
                int c = g8 * 8 + j;
                o[j] = (c < 22) ? bf16rne(v[c]) : (unsigned short)0;
            }
            *(ushort8v*)(op + g8 * 8) = o;
        }
        return;
    }
    int e = blockIdx.x * 256 + threadIdx.x;
    if (e >= E) return;
    int p = atomicAdd(&cursor[dst[e]], 1);
    float ex = ea[2 * e], ey = ea[2 * e + 1];
    float sb = __int_as_float(src[e]);
    float3 g0 = gauss3(ex, ey, mu0, sg0);
    float3 g1 = gauss3(ex, ey, mu1, sg1);
    float3 g2 = gauss3(ex, ey, mu2, sg2);
    g0b[p] = make_float4(sb, g0.x, g0.y, g0.z);
    g1b[p] = make_float4(sb, g1.x, g1.y, g1.z);
    g2b[p] = make_float4(sb, g2.x, g2.y, g2.z);
}

// ---- transposed bf16 weights Wcb[n][k], k-major, ALL 3 layers in ONE launch ----
template <int CIN, int CINP, int COUTR>
static __device__ __forceinline__ void wcb_emit(int t, const float* __restrict__ g,
                                                const float* __restrict__ root,
                                                unsigned short* __restrict__ Wcb) {
    constexpr int KTl = 4 * CINP;
    int nIdx = t / KTl, k = t - nIdx * KTl;
    int seg = k / CINP, c = k - seg * CINP;
    float v = 0.0f;
    if (c < CIN)
        v = (seg < 3) ? g[c * (3 * COUTR) + seg * COUTR + nIdx] : root[c * COUTR + nIdx];
    Wcb[t] = bf16rne(v);
}

__global__ __launch_bounds__(256) void build_all_wcb(const float* __restrict__ g0, const float* __restrict__ rt0,
                                                     const float* __restrict__ g1, const float* __restrict__ rt1,
                                                     const float* __restrict__ g2, const float* __restrict__ rt2,
                                                     unsigned short* __restrict__ W0,
                                                     unsigned short* __restrict__ W1,
                                                     unsigned short* __restrict__ W2) {
    int t = blockIdx.x * 256 + threadIdx.x;
    constexpr int T0 = 32 * 128, T1 = 64 * 128, T2 = 64 * 256;
    if (t < T0)                wcb_emit<22, 32, 32>(t, g0, rt0, W0);
    else if (t < T0 + T1)      wcb_emit<32, 32, 64>(t - T0, g1, rt1, W1);
    else if (t < T0 + T1 + T2) wcb_emit<64, 64, 64>(t - T0 - T1, g2, rt2, W2);
}

static __device__ __forceinline__ void fma4(float4& a, float g, const float4& hv) {
    a.x = fmaf(g, hv.x, a.x);
    a.y = fmaf(g, hv.y, a.y);
    a.z = fmaf(g, hv.z, a.z);
    a.w = fmaf(g, hv.w, a.w);
}

// ============ FUSED layer: aggregate (16-B bf16 gather) -> bf16 LDS tile -> MFMA ============
// Gather-latency-bound kernel (HBM 14%, VALU 20%, MFMA 2.4%, Occ 34% in round 19).
// Levers this round:
//  * NT=512 for layer 2: 4 blk/CU x 8 waves = 32 waves/CU (occupancy ceiling 50%->100%);
//    LDS 4x33792=135168 <= 163840, threads 2048 = CU cap. __launch_bounds__(NT,8) pins
//    VGPR<=64 (was 60). Spill tripwire = WRITE_SIZE.
//  * Predicated full batches: clamp index, zero gaussian weights for p+u>=end. Removes
//    the serial 1-gather-at-a-time remainder loop (deg%4 edges were each ~600 cy serial).
//  * Phase 2 remap: wave -> fixed column-tile ct=wv%NCT, row-groups rg0+i*RST. B-frag
//    (Wcb, L1-resident) hoisted out of the tile loop; acc[TPW] per wave.
//  * FC=true (layer 2): fuse FC 64->2 + log_softmax through LDS (reuse sa after barrier);
//    kills hC write (21 MB) + final_kernel read (21 MB) + one launch.
// Tile 64 x KT bf16, odd float4 stride conflict-free. MFMA C/D col=lane&15, row=quad*4+reg.
template <int CINP, int COUTR, int NT, bool FC>
__global__ __launch_bounds__(NT, 8) void fused_mfma(const unsigned short* __restrict__ h, int hs,
                                                    const float4* __restrict__ ged,
                                                    const int* __restrict__ cursor,
                                                    const int* __restrict__ degi,
                                                    const unsigned short* __restrict__ Wcb,
                                                    const float* __restrict__ bias,
                                                    unsigned short* __restrict__ out,
                                                    const float* __restrict__ fcw,
                                                    const float* __restrict__ fcb,
                                                    float* __restrict__ fout, int n) {
    constexpr int KT    = 4 * CINP;
    constexpr int ST4   = KT / 8 + 1;            // float4 per LDS row (odd)
    constexpr int ROWU  = ST4 * 8;               // ushorts per LDS row
    constexpr int NSTEP = KT / 32;
    constexpr int NCT   = COUTR / 16;
    constexpr int LPN   = CINP / 8;              // lanes per node
    constexpr int NPP   = NT / LPN;              // nodes per pass
    static_assert(NPP == 64, "single pass over the 64-node tile");
    __shared__ float4 sa[64 * ST4];
    unsigned short* st = (unsigned short*)sa;
    const int row0 = blockIdx.x * 64;

    // ---------------- phase 1: aggregate + own-h into bf16 LDS tile ----------------
    {
        const int sub = threadIdx.x / LPN;
        const int li  = threadIdx.x % LPN;       // covers bf16 [li*8, li*8+8)
        int node = row0 + sub; if (node > n - 1) node = n - 1;
        int end = cursor[node];
        int dg  = degi[node];
        int p   = end - dg;
        float4 a[3][2];
#pragma unroll
        for (int k = 0; k < 3; ++k)
#pragma unroll
            for (int q = 0; q < 2; ++q) a[k][q] = make_float4(0, 0, 0, 0);
        for (; p < end; p += 4) {                // predicated full batch: 4 gathers in flight
            float4 ed[4];
            ushort8v hu[4];
#pragma unroll
            for (int u = 0; u < 4; ++u) {
                int q = p + u;
                ed[u] = ged[(q < end) ? q : (end - 1)];
            }
#pragma unroll
            for (int u = 0; u < 4; ++u)
                if (p + u >= end) { ed[u].y = 0.0f; ed[u].z = 0.0f; ed[u].w = 0.0f; }
#pragma unroll
            for (int u = 0; u < 4; ++u)
                hu[u] = *(const ushort8v*)(h + (long)__float_as_int(ed[u].x) * hs + li * 8);
#pragma unroll
            for (int u = 0; u < 4; ++u) {
                float4 h0 = make_float4(bf2f(hu[u][0]), bf2f(hu[u][1]),
                                        bf2f(hu[u][2]), bf2f(hu[u][3]));
                float4 h1 = make_float4(bf2f(hu[u][4]), bf2f(hu[u][5]),
                                        bf2f(hu[u][6]), bf2f(hu[u][7]));
                fma4(a[0][0], ed[u].y, h0); fma4(a[0][1], ed[u].y, h1);
                fma4(a[1][0], ed[u].z, h0); fma4(a[1][1], ed[u].z, h1);
                fma4(a[2][0], ed[u].w, h0); fma4(a[2][1], ed[u].w, h1);
            }
        }
        float inv = 1.0f / (float)max(dg, 1);
#pragma unroll
        for (int k = 0; k < 3; ++k)
#pragma unroll
            for (int q = 0; q < 2; ++q) fma4(a[k][q], inv - 1.0f, a[k][q]);  // *= inv
        ushort8v hv8 = *(const ushort8v*)(h + (long)node * hs + li * 8);     // raw bf16
        int base = sub * ROWU;
        int c8b  = li * 8;
#pragma unroll
        for (int k = 0; k < 3; ++k) {
            ushort8v v;
            v[0] = bf16rne(a[k][0].x); v[1] = bf16rne(a[k][0].y);
            v[2] = bf16rne(a[k][0].z); v[3] = bf16rne(a[k][0].w);
            v[4] = bf16rne(a[k][1].x); v[5] = bf16rne(a[k][1].y);
            v[6] = bf16rne(a[k][1].z); v[7] = bf16rne(a[k][1].w);
            *(ushort8v*)(st + base + k * CINP + c8b) = v;
        }
        *(ushort8v*)(st + base + 3 * CINP + c8b) = hv8;
    }
    __syncthreads();

    // ---------------- phase 2: MFMA GEMM from LDS tile ----------------
    constexpr int NW    = NT / 64;               // waves per block
    constexpr int TILES = 4 * NCT;               // 4 row-groups x NCT col-tiles
    constexpr int TPW   = TILES / NW;
    constexpr int RST   = NW / NCT;              // row-group stride per wave
    static_assert(NW % NCT == 0 && TILES % NW == 0, "tile remap");
    const int lane = threadIdx.x & 63;
    const int wv   = threadIdx.x >> 6;
    const int quad = lane >> 4;
    const int c16  = lane & 15;
    const int ct   = wv % NCT;                   // fixed column-tile per wave
    const int rg0  = wv / NCT;
    f32x4 acc[TPW];
#pragma unroll
    for (int i = 0; i < TPW; ++i) acc[i] = (f32x4){0.0f, 0.0f, 0.0f, 0.0f};
    const unsigned short* bcol = Wcb + (ct * 16 + c16) * KT;
#pragma unroll
    for (int s = 0; s < NSTEP; ++s) {
        short8 bf = *(const short8*)(bcol + s * 32 + quad * 8);  // hoisted: same ct all tiles
#pragma unroll
        for (int i = 0; i < TPW; ++i) {
            const unsigned short* arow = st + (16 * (rg0 + i * RST) + c16) * ROWU;
            short8 af = *(const short8*)(arow + s * 32 + quad * 8);
            acc[i] = __builtin_amdgcn_mfma_f32_16x16x32_bf16(af, bf, acc[i], 0, 0, 0);
        }
    }
    if constexpr (!FC) {
        // epilogue: C/D col=lane&15, row=quad*4+reg; write bf16
#pragma unroll
        for (int i = 0; i < TPW; ++i) {
            int rg  = rg0 + i * RST;
            int col = ct * 16 + c16;
            float b = bias[col];
#pragma unroll
            for (int r = 0; r < 4; ++r) {
                int grow = row0 + rg * 16 + quad * 4 + r;
                if (grow < n)
                    out[(long)grow * COUTR + col] = bf16rne(fmaxf(acc[i][r] + b, 0.0f));
            }
        }
    } else {
        // fused FC(64->2)+log_softmax: relu'd bf16 row -> LDS (reuse sa) -> per-node dot
        static_assert(COUTR == 64, "FC fusion assumes 64-wide rows");
        constexpr int FS = 72;                   // ushort stride, 144 B rows (16-B aligned)
        __syncthreads();                         // all MFMA LDS reads complete
        {
            int col = ct * 16 + c16;
            float b = bias[col];
#pragma unroll
            for (int i = 0; i < TPW; ++i) {
                int rg = rg0 + i * RST;
#pragma unroll
                for (int r = 0; r < 4; ++r) {
                    int lr2 = rg * 16 + quad * 4 + r;
                    st[lr2 * FS + col] = bf16rne(fmaxf(acc[i][r] + b, 0.0f));
                }
            }
        }
        __syncthreads();
        int t = threadIdx.x;
        if (t < 64) {
            int node = row0 + t;
            if (node < n) {
                const ushort8v* hr = (const ushort8v*)(st + t * FS);
                float l0 = fcb[0];
                float l1 = fcb[1];
#pragma unroll
                for (int j8 = 0; j8 < 8; ++j8) {
                    ushort8v hv = hr[j8];
#pragma unroll
                    for (int j = 0; j < 8; ++j) {
                        float hvf = bf2f(hv[j]);
                        l0 = fmaf(hvf, fcw[2 * (8 * j8 + j)], l0);
                        l1 = fmaf(hvf, fcw[2 * (8 * j8 + j) + 1], l1);
                    }
                }
                float mx  = fmaxf(l0, l1);
                float lse = mx + logf(__expf(l0 - mx) + __expf(l1 - mx));
                fout[2 * (long)node]     = l0 - lse;
                fout[2 * (long)node + 1] = l1 - lse;
            }
        }
    }
}

extern "C" void kernel_launch(void* const* d_in, const int* in_sizes, int n_in,
                              void* d_out, int out_size, void* d_ws, size_t ws_size,
                              hipStream_t stream) {
    const float* x   = (const float*)d_in[0];
    const int*   ei  = (const int*)d_in[1];
    const float* ea  = (const float*)d_in[2];
    const float* g_[3]  = {(const float*)d_in[3],  (const float*)d_in[8],  (const float*)d_in[13]};
    const float* mu_[3] = {(const float*)d_in[4],  (const float*)d_in[9],  (const float*)d_in[14]};
    const float* sg_[3] = {(const float*)d_in[5],  (const float*)d_in[10], (const float*)d_in[15]};
    const float* rt_[3] = {(const float*)d_in[6],  (const float*)d_in[11], (const float*)d_in[16]};
    const float* bs_[3] = {(const float*)d_in[7],  (const float*)d_in[12], (const float*)d_in[17]};
    const float* fcw = (const float*)d_in[18];
    const float* fcb = (const float*)d_in[19];
    float* out = (float*)d_out;
    (void)in_sizes; (void)n_in; (void)out_size; (void)ws_size;

    // workspace carve-up (~75 MB)
    char* w = (char*)d_ws;
    size_t off = 0;
    auto carve = [&](size_t bytes) -> void* {
        void* p = (void*)(w + off);
        off += (bytes + 255) & ~(size_t)255;
        return p;
    };
    int*    degi   = (int*)carve((size_t)NN * 4);
    int*    cursor = (int*)carve((size_t)NN * 4);
    float4* ged0   = (float4*)carve((size_t)NE * 16);
    float4* ged1   = (float4*)carve((size_t)NE * 16);
    float4* ged2   = (float4*)carve((size_t)NE * 16);
    int*    bsum   = (int*)carve(1024 * 4);
    unsigned short* W0 = (unsigned short*)carve((size_t)32 * 128 * 2);
    unsigned short* W1 = (unsigned short*)carve((size_t)64 * 128 * 2);
    unsigned short* W2 = (unsigned short*)carve((size_t)64 * 256 * 2);
    unsigned short* xp = (unsigned short*)carve((size_t)NN * 32 * 2);  // bf16 [N,32]
    unsigned short* hA = (unsigned short*)carve((size_t)NN * 32 * 2);  // bf16 [N,32]
    unsigned short* hB = (unsigned short*)carve((size_t)NN * 64 * 2);  // bf16 [N,64]

    const int* src = ei;
    const int* dst = ei + NE;
    const int EB = (NE + 255) / 256;
    const int PB = (NN + 255) / 256;  // pad blocks appended to scatter grid
    const int GB = (NN + 63) / 64;    // 2561 blocks: 64 nodes per block

    // ---- CSR build + all-layer gaussians + x pad (once per call) ----
    hipMemsetAsync(degi, 0, (size_t)NN * 4, stream);
    deg_count<<<EB, 256, 0, stream>>>(dst, degi, NE);
    scan1<<<NB, 256, 0, stream>>>(degi, cursor, bsum, NN);
    scan2<<<1, 1024, 0, stream>>>(bsum, NB);
    scan3<<<NB, 256, 0, stream>>>(cursor, bsum, NN);
    scatter_pad<<<EB + PB, 256, 0, stream>>>(src, dst, ea, cursor,
                                             mu_[0], sg_[0], mu_[1], sg_[1], mu_[2], sg_[2],
                                             ged0, ged1, ged2, x, xp, NE, EB, NN);
    build_all_wcb<<<112, 256, 0, stream>>>(g_[0], rt_[0], g_[1], rt_[1], g_[2], rt_[2],
                                           W0, W1, W2);

    // ---- layer 0: 22(pad32) -> 32 ----
    fused_mfma<32, 32, 256, false><<<GB, 256, 0, stream>>>(xp, 32, ged0, cursor, degi,
                                                           W0, bs_[0], hA, nullptr, nullptr,
                                                           nullptr, NN);
    // ---- layer 1: 32 -> 64 ----
    fused_mfma<32, 64, 256, false><<<GB, 256, 0, stream>>>(hA, 32, ged1, cursor, degi,
                                                           W1, bs_[1], hB, nullptr, nullptr,
                                                           nullptr, NN);
    // ---- layer 2: 64 -> 64, 512 threads (32 waves/CU), fused FC + log_softmax ----
    fused_mfma<64, 64, 512, true><<<GB, 512, 0, stream>>>(hB, 64, ged2, cursor, degi,
                                                          W2, bs_[2], nullptr, fcw, fcb,
                                                          out, NN);
}

// Round 2
// 347.117 us; speedup vs baseline: 1.1525x; 1.1053x over previous
//
#include <hip/hip_runtime.h>

#define NN 163842
#define NE 983040
#define NB 641   // ceil(NN/256)

using short8   = __attribute__((ext_vector_type(8))) short;
using ushort8v = __attribute__((ext_vector_type(8))) unsigned short;
using f32x4    = __attribute__((ext_vector_type(4))) float;

// ---------------- degree count (int) ----------------
__global__ __launch_bounds__(256) void deg_count(const int* __restrict__ dst,
                                                 int* __restrict__ degi, int E) {
    int e = blockIdx.x * 256 + threadIdx.x;
    if (e < E) atomicAdd(&degi[dst[e]], 1);
}

// ---------------- exclusive scan of degi -> cursor ----------------
__global__ __launch_bounds__(256) void scan1(const int* __restrict__ degi,
                                             int* __restrict__ cursor,
                                             int* __restrict__ bsum, int n) {
    __shared__ int tmp[256];
    int t = threadIdx.x;
    int i = blockIdx.x * 256 + t;
    int v = (i < n) ? degi[i] : 0;
    tmp[t] = v;
    __syncthreads();
    for (int o = 1; o < 256; o <<= 1) {
        int x = (t >= o) ? tmp[t - o] : 0;
        __syncthreads();
        tmp[t] += x;
        __syncthreads();
    }
    if (i < n) cursor[i] = tmp[t] - v;            // exclusive
    if (t == 255) bsum[blockIdx.x] = tmp[255];    // block total
}

__global__ void scan2(int* __restrict__ bsum, int nb) {
    __shared__ int tmp[1024];
    int t = threadIdx.x;
    int v = (t < nb) ? bsum[t] : 0;
    tmp[t] = v;
    __syncthreads();
    for (int o = 1; o < 1024; o <<= 1) {
        int x = (t >= o) ? tmp[t - o] : 0;
        __syncthreads();
        tmp[t] += x;
        __syncthreads();
    }
    if (t < nb) bsum[t] = tmp[t] - v;
}

__global__ __launch_bounds__(256) void scan3(int* __restrict__ cursor,
                                             const int* __restrict__ bsum, int n) {
    int i = blockIdx.x * 256 + threadIdx.x;
    if (i < n) cursor[i] += bsum[blockIdx.x];
}

static __device__ __forceinline__ unsigned short bf16rne(float x) {
    unsigned u = __float_as_uint(x);
    u += 0x7FFFu + ((u >> 16) & 1u);      // round-to-nearest-even
    return (unsigned short)(u >> 16);
}

static __device__ __forceinline__ float bf2f(unsigned short u) {
    return __uint_as_float(((unsigned)u) << 16);
}

// ---- scatter CSR-ordered edge records {src, ex, ey, _} (16 B/edge, was 48 B) ----
// One 16-B random write/edge instead of three: WRITE_SIZE 135 MB -> ~1 line/edge.
// Gaussians moved into fused_mfma (they overlap gather latency there).
// blocks [0, EBLK): per-edge scatter; blocks [EBLK, EBLK+PB): pad x [N,22] -> xp [N,32] bf16.
__global__ __launch_bounds__(256) void scatter_pad(const int* __restrict__ src,
                                                   const int* __restrict__ dst,
                                                   const float* __restrict__ ea,
                                                   int* __restrict__ cursor,
                                                   float4* __restrict__ gedr,
                                                   const float* __restrict__ x,
                                                   unsigned short* __restrict__ xp,
                                                   int E, int EBLK, int n) {
    if ((int)blockIdx.x >= EBLK) {
        // ---- pad path: one thread per node, float2 loads + ushort8 stores ----
        int r = (blockIdx.x - EBLK) * 256 + threadIdx.x;
        if (r >= n) return;
        float v[22];
        const float2* x2 = (const float2*)(x + (size_t)r * 22);  // 88 B row, 8-aligned
#pragma unroll
        for (int j = 0; j < 11; ++j) *(float2*)(v + 2 * j) = x2[j];
        unsigned short* op = xp + (size_t)r * 32;
#pragma unroll
        for (int g8 = 0; g8 < 4; ++g8) {
            ushort8v o;
#pragma unroll
            for (int j = 0; j < 8; ++j) {
                int c = g8 * 8 + j;
                o[j] = (c < 22) ? bf16rne(v[c]) : (unsigned short)0;
            }
            *(ushort8v*)(op + g8 * 8) = o;
        }
        return;
    }
    int e = blockIdx.x * 256 + threadIdx.x;
    if (e >= E) return;
    int p = atomicAdd(&cursor[dst[e]], 1);
    gedr[p] = make_float4(__int_as_float(src[e]), ea[2 * e], ea[2 * e + 1], 0.0f);
}

// ---- transposed bf16 weights Wcb[n][k], k-major, ALL 3 layers in ONE launch ----
template <int CIN, int CINP, int COUTR>
static __device__ __forceinline__ void wcb_emit(int t, const float* __restrict__ g,
                                                const float* __restrict__ root,
                                                unsigned short* __restrict__ Wcb) {
    constexpr int KTl = 4 * CINP;
    int nIdx = t / KTl, k = t - nIdx * KTl;
    int seg = k / CINP, c = k - seg * CINP;
    float v = 0.0f;
    if (c < CIN)
        v = (seg < 3) ? g[c * (3 * COUTR) + seg * COUTR + nIdx] : root[c * COUTR + nIdx];
    Wcb[t] = bf16rne(v);
}

__global__ __launch_bounds__(256) void build_all_wcb(const float* __restrict__ g0, const float* __restrict__ rt0,
                                                     const float* __restrict__ g1, const float* __restrict__ rt1,
                                                     const float* __restrict__ g2, const float* __restrict__ rt2,
                                                     unsigned short* __restrict__ W0,
                                                     unsigned short* __restrict__ W1,
                                                     unsigned short* __restrict__ W2) {
    int t = blockIdx.x * 256 + threadIdx.x;
    constexpr int T0 = 32 * 128, T1 = 64 * 128, T2 = 64 * 256;
    if (t < T0)                wcb_emit<22, 32, 32>(t, g0, rt0, W0);
    else if (t < T0 + T1)      wcb_emit<32, 32, 64>(t - T0, g1, rt1, W1);
    else if (t < T0 + T1 + T2) wcb_emit<64, 64, 64>(t - T0 - T1, g2, rt2, W2);
}

static __device__ __forceinline__ void fma4(float4& a, float g, const float4& hv) {
    a.x = fmaf(g, hv.x, a.x);
    a.y = fmaf(g, hv.y, a.y);
    a.z = fmaf(g, hv.z, a.z);
    a.w = fmaf(g, hv.w, a.w);
}

// 3 gaussian weights from edge pseudo-coords; muv/ccv constant-indexed -> registers/SGPRs.
static __device__ __forceinline__ float3 gauss3c(float ex, float ey,
                                                 const float* muv, const float* ccv) {
    float3 r;
    float dx, dy;
    dx = ex - muv[0]; dy = ey - muv[1];
    r.x = __expf(fmaf(ccv[0] * dx, dx, ccv[1] * dy * dy));
    dx = ex - muv[2]; dy = ey - muv[3];
    r.y = __expf(fmaf(ccv[2] * dx, dx, ccv[3] * dy * dy));
    dx = ex - muv[4]; dy = ey - muv[5];
    r.z = __expf(fmaf(ccv[4] * dx, dx, ccv[5] * dy * dy));
    return r;
}

// ============ FUSED layer: aggregate (16-B bf16 gather) -> bf16 LDS tile -> MFMA ============
// Round-1 lesson: __launch_bounds__(NT,8) => 64-VGPR budget; batch-4 predicated loop
// spilled (VGPR=32 + WRITE_SIZE 92 MB scratch). Round 2: BATCH=2 (frees ~16 VGPR,
// ~50 live -> no spill) — MLP preserved via occupancy: 32 waves/CU x 2 in flight.
// Gaussians computed here from the {src,ex,ey} record (overlap gather latency).
// NT=512 layer 2: LDS 4x33792=135168 <= 160K, 4 blk x 8 waves = 32 waves/CU.
// Tile 64 x KT bf16, odd float4 stride conflict-free. MFMA C/D col=lane&15, row=quad*4+reg.
// FC=true: fused FC 64->2 + log_softmax through LDS (no hC traffic, no extra launch).
template <int CINP, int COUTR, int NT, bool FC>
__global__ __launch_bounds__(NT, 8) void fused_mfma(const unsigned short* __restrict__ h, int hs,
                                                    const float4* __restrict__ ged,
                                                    const int* __restrict__ cursor,
                                                    const int* __restrict__ degi,
                                                    const unsigned short* __restrict__ Wcb,
                                                    const float* __restrict__ bias,
                                                    const float* __restrict__ mu,
                                                    const float* __restrict__ sg,
                                                    unsigned short* __restrict__ out,
                                                    const float* __restrict__ fcw,
                                                    const float* __restrict__ fcb,
                                                    float* __restrict__ fout, int n) {
    constexpr int KT    = 4 * CINP;
    constexpr int ST4   = KT / 8 + 1;            // float4 per LDS row (odd)
    constexpr int ROWU  = ST4 * 8;               // ushorts per LDS row
    constexpr int NSTEP = KT / 32;
    constexpr int NCT   = COUTR / 16;
    constexpr int LPN   = CINP / 8;              // lanes per node
    constexpr int NPP   = NT / LPN;              // nodes per pass
    static_assert(NPP == 64, "single pass over the 64-node tile");
    __shared__ float4 sa[64 * ST4];
    unsigned short* st = (unsigned short*)sa;
    const int row0 = blockIdx.x * 64;

    // ---------------- phase 1: aggregate + own-h into bf16 LDS tile ----------------
    {
        float muv[6], ccv[6];
#pragma unroll
        for (int j = 0; j < 6; ++j) muv[j] = mu[j];
#pragma unroll
        for (int j = 0; j < 6; ++j) {
            float s = sg[j];
            ccv[j] = -0.5f / (1e-15f + s * s);
        }
        const int sub = threadIdx.x / LPN;
        const int li  = threadIdx.x % LPN;       // covers bf16 [li*8, li*8+8)
        int node = row0 + sub; if (node > n - 1) node = n - 1;
        int end = cursor[node];
        int dg  = degi[node];
        int p   = end - dg;
        float4 a[3][2];
#pragma unroll
        for (int k = 0; k < 3; ++k)
#pragma unroll
            for (int q = 0; q < 2; ++q) a[k][q] = make_float4(0, 0, 0, 0);
        for (; p < end; p += 2) {                // predicated batch-2: 2 gathers in flight
            int q1 = (p + 1 < end) ? (p + 1) : p;
            float4 ed0 = ged[p];
            float4 ed1 = ged[q1];
            ushort8v hu0 = *(const ushort8v*)(h + (long)__float_as_int(ed0.x) * hs + li * 8);
            ushort8v hu1 = *(const ushort8v*)(h + (long)__float_as_int(ed1.x) * hs + li * 8);
            float3 g0 = gauss3c(ed0.y, ed0.z, muv, ccv);
            float3 g1 = gauss3c(ed1.y, ed1.z, muv, ccv);
            if (p + 1 >= end) { g1.x = 0.0f; g1.y = 0.0f; g1.z = 0.0f; }
            {
                float4 h0 = make_float4(bf2f(hu0[0]), bf2f(hu0[1]), bf2f(hu0[2]), bf2f(hu0[3]));
                float4 h1 = make_float4(bf2f(hu0[4]), bf2f(hu0[5]), bf2f(hu0[6]), bf2f(hu0[7]));
                fma4(a[0][0], g0.x, h0); fma4(a[0][1], g0.x, h1);
                fma4(a[1][0], g0.y, h0); fma4(a[1][1], g0.y, h1);
                fma4(a[2][0], g0.z, h0); fma4(a[2][1], g0.z, h1);
            }
            {
                float4 h0 = make_float4(bf2f(hu1[0]), bf2f(hu1[1]), bf2f(hu1[2]), bf2f(hu1[3]));
                float4 h1 = make_float4(bf2f(hu1[4]), bf2f(hu1[5]), bf2f(hu1[6]), bf2f(hu1[7]));
                fma4(a[0][0], g1.x, h0); fma4(a[0][1], g1.x, h1);
                fma4(a[1][0], g1.y, h0); fma4(a[1][1], g1.y, h1);
                fma4(a[2][0], g1.z, h0); fma4(a[2][1], g1.z, h1);
            }
        }
        float inv = 1.0f / (float)max(dg, 1);
#pragma unroll
        for (int k = 0; k < 3; ++k)
#pragma unroll
            for (int q = 0; q < 2; ++q) fma4(a[k][q], inv - 1.0f, a[k][q]);  // *= inv
        ushort8v hv8 = *(const ushort8v*)(h + (long)node * hs + li * 8);     // raw bf16
        int base = sub * ROWU;
        int c8b  = li * 8;
#pragma unroll
        for (int k = 0; k < 3; ++k) {
            ushort8v v;
            v[0] = bf16rne(a[k][0].x); v[1] = bf16rne(a[k][0].y);
            v[2] = bf16rne(a[k][0].z); v[3] = bf16rne(a[k][0].w);
            v[4] = bf16rne(a[k][1].x); v[5] = bf16rne(a[k][1].y);
            v[6] = bf16rne(a[k][1].z); v[7] = bf16rne(a[k][1].w);
            *(ushort8v*)(st + base + k * CINP + c8b) = v;
        }
        *(ushort8v*)(st + base + 3 * CINP + c8b) = hv8;
    }
    __syncthreads();

    // ---------------- phase 2: MFMA GEMM from LDS tile ----------------
    constexpr int NW    = NT / 64;               // waves per block
    constexpr int TILES = 4 * NCT;               // 4 row-groups x NCT col-tiles
    constexpr int TPW   = TILES / NW;
    constexpr int RST   = NW / NCT;              // row-group stride per wave
    static_assert(NW % NCT == 0 && TILES % NW == 0, "tile remap");
    const int lane = threadIdx.x & 63;
    const int wv   = threadIdx.x >> 6;
    const int quad = lane >> 4;
    const int c16  = lane & 15;
    const int ct   = wv % NCT;                   // fixed column-tile per wave
    const int rg0  = wv / NCT;
    f32x4 acc[TPW];
#pragma unroll
    for (int i = 0; i < TPW; ++i) acc[i] = (f32x4){0.0f, 0.0f, 0.0f, 0.0f};
    const unsigned short* bcol = Wcb + (ct * 16 + c16) * KT;
#pragma unroll
    for (int s = 0; s < NSTEP; ++s) {
        short8 bf = *(const short8*)(bcol + s * 32 + quad * 8);  // hoisted: same ct all tiles
#pragma unroll
        for (int i = 0; i < TPW; ++i) {
            const unsigned short* arow = st + (16 * (rg0 + i * RST) + c16) * ROWU;
            short8 af = *(const short8*)(arow + s * 32 + quad * 8);
            acc[i] = __builtin_amdgcn_mfma_f32_16x16x32_bf16(af, bf, acc[i], 0, 0, 0);
        }
    }
    if constexpr (!FC) {
        // epilogue: C/D col=lane&15, row=quad*4+reg; write bf16
#pragma unroll
        for (int i = 0; i < TPW; ++i) {
            int rg  = rg0 + i * RST;
            int col = ct * 16 + c16;
            float b = bias[col];
#pragma unroll
            for (int r = 0; r < 4; ++r) {
                int grow = row0 + rg * 16 + quad * 4 + r;
                if (grow < n)
                    out[(long)grow * COUTR + col] = bf16rne(fmaxf(acc[i][r] + b, 0.0f));
            }
        }
    } else {
        // fused FC(64->2)+log_softmax: relu'd bf16 row -> LDS (reuse sa) -> per-node dot
        static_assert(COUTR == 64, "FC fusion assumes 64-wide rows");
        constexpr int FS = 72;                   // ushort stride, 144 B rows (16-B aligned)
        __syncthreads();                         // all MFMA LDS reads complete
        {
            int col = ct * 16 + c16;
            float b = bias[col];
#pragma unroll
            for (int i = 0; i < TPW; ++i) {
                int rg = rg0 + i * RST;
#pragma unroll
                for (int r = 0; r < 4; ++r) {
                    int lr2 = rg * 16 + quad * 4 + r;
                    st[lr2 * FS + col] = bf16rne(fmaxf(acc[i][r] + b, 0.0f));
                }
            }
        }
        __syncthreads();
        int t = threadIdx.x;
        if (t < 64) {
            int node = row0 + t;
            if (node < n) {
                const ushort8v* hr = (const ushort8v*)(st + t * FS);
                float l0 = fcb[0];
                float l1 = fcb[1];
#pragma unroll
                for (int j8 = 0; j8 < 8; ++j8) {
                    ushort8v hv = hr[j8];
#pragma unroll
                    for (int j = 0; j < 8; ++j) {
                        float hvf = bf2f(hv[j]);
                        l0 = fmaf(hvf, fcw[2 * (8 * j8 + j)], l0);
                        l1 = fmaf(hvf, fcw[2 * (8 * j8 + j) + 1], l1);
                    }
                }
                float mx  = fmaxf(l0, l1);
                float lse = mx + logf(__expf(l0 - mx) + __expf(l1 - mx));
                fout[2 * (long)node]     = l0 - lse;
                fout[2 * (long)node + 1] = l1 - lse;
            }
        }
    }
}

extern "C" void kernel_launch(void* const* d_in, const int* in_sizes, int n_in,
                              void* d_out, int out_size, void* d_ws, size_t ws_size,
                              hipStream_t stream) {
    const float* x   = (const float*)d_in[0];
    const int*   ei  = (const int*)d_in[1];
    const float* ea  = (const float*)d_in[2];
    const float* g_[3]  = {(const float*)d_in[3],  (const float*)d_in[8],  (const float*)d_in[13]};
    const float* mu_[3] = {(const float*)d_in[4],  (const float*)d_in[9],  (const float*)d_in[14]};
    const float* sg_[3] = {(const float*)d_in[5],  (const float*)d_in[10], (const float*)d_in[15]};
    const float* rt_[3] = {(const float*)d_in[6],  (const float*)d_in[11], (const float*)d_in[16]};
    const float* bs_[3] = {(const float*)d_in[7],  (const float*)d_in[12], (const float*)d_in[17]};
    const float* fcw = (const float*)d_in[18];
    const float* fcb = (const float*)d_in[19];
    float* out = (float*)d_out;
    (void)in_sizes; (void)n_in; (void)out_size; (void)ws_size;

    // workspace carve-up (~45 MB)
    char* w = (char*)d_ws;
    size_t off = 0;
    auto carve = [&](size_t bytes) -> void* {
        void* p = (void*)(w + off);
        off += (bytes + 255) & ~(size_t)255;
        return p;
    };
    int*    degi   = (int*)carve((size_t)NN * 4);
    int*    cursor = (int*)carve((size_t)NN * 4);
    float4* gedr   = (float4*)carve((size_t)NE * 16);   // {src, ex, ey, _} CSR-ordered
    int*    bsum   = (int*)carve(1024 * 4);
    unsigned short* W0 = (unsigned short*)carve((size_t)32 * 128 * 2);
    unsigned short* W1 = (unsigned short*)carve((size_t)64 * 128 * 2);
    unsigned short* W2 = (unsigned short*)carve((size_t)64 * 256 * 2);
    unsigned short* xp = (unsigned short*)carve((size_t)NN * 32 * 2);  // bf16 [N,32]
    unsigned short* hA = (unsigned short*)carve((size_t)NN * 32 * 2);  // bf16 [N,32]
    unsigned short* hB = (unsigned short*)carve((size_t)NN * 64 * 2);  // bf16 [N,64]

    const int* src = ei;
    const int* dst = ei + NE;
    const int EB = (NE + 255) / 256;
    const int PB = (NN + 255) / 256;  // pad blocks appended to scatter grid
    const int GB = (NN + 63) / 64;    // 2561 blocks: 64 nodes per block

    // ---- CSR build + edge records + x pad (once per call) ----
    hipMemsetAsync(degi, 0, (size_t)NN * 4, stream);
    deg_count<<<EB, 256, 0, stream>>>(dst, degi, NE);
    scan1<<<NB, 256, 0, stream>>>(degi, cursor, bsum, NN);
    scan2<<<1, 1024, 0, stream>>>(bsum, NB);
    scan3<<<NB, 256, 0, stream>>>(cursor, bsum, NN);
    scatter_pad<<<EB + PB, 256, 0, stream>>>(src, dst, ea, cursor,
                                             gedr, x, xp, NE, EB, NN);
    build_all_wcb<<<112, 256, 0, stream>>>(g_[0], rt_[0], g_[1], rt_[1], g_[2], rt_[2],
                                           W0, W1, W2);

    // ---- layer 0: 22(pad32) -> 32 ----
    fused_mfma<32, 32, 256, false><<<GB, 256, 0, stream>>>(xp, 32, gedr, cursor, degi,
                                                           W0, bs_[0], mu_[0], sg_[0],
                                                           hA, nullptr, nullptr,
                                                           nullptr, NN);
    // ---- layer 1: 32 -> 64 ----
    fused_mfma<32, 64, 256, false><<<GB, 256, 0, stream>>>(hA, 32, gedr, cursor, degi,
                                                           W1, bs_[1], mu_[1], sg_[1],
                                                           hB, nullptr, nullptr,
                                                           nullptr, NN);
    // ---- layer 2: 64 -> 64, 512 threads (32 waves/CU), fused FC + log_softmax ----
    fused_mfma<64, 64, 512, true><<<GB, 512, 0, stream>>>(hB, 64, gedr, cursor, degi,
                                                          W2, bs_[2], mu_[2], sg_[2],
                                                          nullptr, fcw, fcb,
                                                          out, NN);
}